// Round 1
// baseline (489.530 us; speedup 1.0000x reference)
//
#include <hip/hip_runtime.h>

#define LOG2E 1.4426950408889634f
#define LN2   0.6931471805599453f

// 4 waves per block, one block per batch element. The 64-state score vector
// is kept REPLICATED in every wave (per-lane ops are deterministic, so the
// replicas stay bit-identical and each wave can v_readlane any w[j] from its
// own copy). Each wave accumulates a 16-wide j-slice of the matvec
//   s[i] = sum_j M[i,j] * 2^(score2[j]-a2),
// exchanges partials through double-buffered LDS with ONE barrier per step,
// then all waves redundantly finish (combine + log2 + emit).
//
// Rationale (round-3 counters): 512 single-wave blocks = 0.5 waves/SIMD,
// VALUBusy 18%, occupancy 3.1% -> latency-bound with exposed serial chain.
// Splitting j across 4 waves quarters the per-wave issue per step AND gives
// 2048 waves (2/SIMD), so independent blocks hide each other's stalls.
__device__ __forceinline__ float bcast(float v, int l) {
  return __uint_as_float(__builtin_amdgcn_readlane(__float_as_uint(v), l));
}

__global__ __launch_bounds__(256, 2) void crf_fwd_33852932227637(
    const float* __restrict__ h,
    const float* __restrict__ trans,
    const int* __restrict__ lengths,
    float* __restrict__ out,
    int T) {
  constexpr int N = 64;
  constexpr int NW = 4;        // waves per block
  constexpr int JW = N / NW;   // j-slice per wave = 16
  const int b = blockIdx.x;
  const int lane = threadIdx.x & 63;
  const int wv = threadIdx.x >> 6;
  const int jbase = wv * JW;

  const float* hb = h + (size_t)b * T * N;

  // M slice for this lane/wave: Ms[k] = exp(trans[lane, jbase+k])  (16 VGPRs)
  float Ms[JW];
  const float4* trow = (const float4*)(trans + lane * N + jbase);
#pragma unroll
  for (int q = 0; q < JW / 4; ++q) {
    float4 tq = trow[q];
    Ms[4 * q + 0] = __builtin_amdgcn_exp2f(tq.x * LOG2E);
    Ms[4 * q + 1] = __builtin_amdgcn_exp2f(tq.y * LOG2E);
    Ms[4 * q + 2] = __builtin_amdgcn_exp2f(tq.z * LOG2E);
    Ms[4 * q + 3] = __builtin_amdgcn_exp2f(tq.w * LOG2E);
  }

  const int len = lengths[b];

  // t=0 closed form (exp(-10000+x)==0 in fp32): score[i]=h[b,0,i]+trans[i,START]
  float score2 = (hb[lane] + trans[lane * N + (N - 2)]) * LOG2E;

  // part[buf][wave][state] — writes lane-contiguous (conflict-free), reads
  // stride 256 B (bank = lane%32, 2-way aliasing = free). Double-buffered so
  // a single barrier per step is race-free: the read of buf is consumed
  // (into score2) before the next write to buf^1 can be computed, and the
  // next barrier precedes any reuse of buf.
  __shared__ float part[2][NW][N];
  int buf = 0;

  auto step = [&](float emit2) {
    float a2 = __uint_as_float(
        __builtin_amdgcn_readfirstlane(__float_as_uint(score2)));
    float w = __builtin_amdgcn_exp2f(score2 - a2);
    float acc0 = 0.f, acc1 = 0.f, acc2 = 0.f, acc3 = 0.f;
#pragma unroll
    for (int k = 0; k < JW; k += 4) {
      acc0 = fmaf(Ms[k + 0], bcast(w, jbase + k + 0), acc0);
      acc1 = fmaf(Ms[k + 1], bcast(w, jbase + k + 1), acc1);
      acc2 = fmaf(Ms[k + 2], bcast(w, jbase + k + 2), acc2);
      acc3 = fmaf(Ms[k + 3], bcast(w, jbase + k + 3), acc3);
    }
    part[buf][wv][lane] = (acc0 + acc1) + (acc2 + acc3);
    __syncthreads();
    float s = (part[buf][0][lane] + part[buf][1][lane]) +
              (part[buf][2][lane] + part[buf][3][lane]);
    score2 = emit2 + a2 + __builtin_amdgcn_logf(s);  // v_log_f32 = log2
    buf ^= 1;
  };

  // Software-pipelined emissions (pre-scaled by log2e), 8 deep, per wave.
  float eb[8];
#pragma unroll
  for (int u = 0; u < 8; ++u) {
    int t0 = 1 + u;
    int tc = t0 < T ? t0 : T - 1;
    eb[u] = hb[(size_t)tc * N + lane] * LOG2E;
  }

  int t = 1;
  for (; t + 8 <= len; t += 8) {
#pragma unroll
    for (int u = 0; u < 8; ++u) {
      step(eb[u]);
      int tn = t + u + 8;
      int tc = tn < T ? tn : T - 1;  // in-bounds; value unused past len
      eb[u] = hb[(size_t)tc * N + lane] * LOG2E;
    }
  }
  for (; t < len; ++t) {  // <=7 tail steps (len is block-uniform: no barrier divergence)
    step(hb[(size_t)t * N + lane] * LOG2E);
  }

  // Terminal transition to END (N-1), then wave-wide logsumexp (natural log).
  // score2 is replicated; wave 0 alone produces the output.
  if (wv == 0) {
    float fin = score2 * LN2 + trans[(N - 1) * N + lane];
    float m = fin;
#pragma unroll
    for (int off = 32; off >= 1; off >>= 1)
      m = fmaxf(m, __shfl_xor(m, off, 64));
    float z = __builtin_amdgcn_exp2f((fin - m) * LOG2E);
#pragma unroll
    for (int off = 32; off >= 1; off >>= 1)
      z += __shfl_xor(z, off, 64);
    if (lane == 0) out[b] = m + LN2 * __builtin_amdgcn_logf(z);
  }
}

extern "C" void kernel_launch(void* const* d_in, const int* in_sizes, int n_in,
                              void* d_out, int out_size, void* d_ws, size_t ws_size,
                              hipStream_t stream) {
  const float* h = (const float*)d_in[0];
  const float* trans = (const float*)d_in[1];
  const int* lengths = (const int*)d_in[2];
  float* out = (float*)d_out;
  const int B = in_sizes[2];
  const int N = 64;
  const int T = in_sizes[0] / (B * N);
  crf_fwd_33852932227637<<<B, N * 4, 0, stream>>>(h, trans, lengths, out, T);
}

// Round 2
// 392.966 us; speedup vs baseline: 1.2457x; 1.2457x over previous
//
#include <hip/hip_runtime.h>

#define LOG2E 1.4426950408889634f
#define LN2   0.6931471805599453f

// One wave (64 lanes) per batch element. Lane i owns state i.
// Recurrence kept in log2 domain:
//   score2'[i] = emit2[i] + a2 + log2( sum_j M[i,j] * 2^(score2[j]-a2) )
// with M[i,j] = exp(trans[i,j]) held in 64 VGPRs per lane (row i).
//
// Round-4 post-mortem: the 4-wave LDS-split regressed (347 vs 261 µs) —
// every per-step cross-wave barrier lands on the serial critical path.
// Round-0's counters showed VGPR_Count=48 for a kernel that needs ~80+
// registers -> Mrow was living in AGPRs/scratch, adding ~2 ops per fma.
// Fix: single-wave structure + amdgpu_waves_per_eu(1,1) (full register
// budget; we only have 0.5 waves/SIMD anyway) + "+v" pins so all 64 M
// values are arch-VGPR-resident across the time loop.
__device__ __forceinline__ float bcast(float v, int l) {
  return __uint_as_float(__builtin_amdgcn_readlane(__float_as_uint(v), l));
}

__global__ __launch_bounds__(64)
__attribute__((amdgpu_waves_per_eu(1, 1)))
void crf_fwd_33852932227637(
    const float* __restrict__ h,
    const float* __restrict__ trans,
    const int* __restrict__ lengths,
    float* __restrict__ out,
    int T) {
  constexpr int N = 64;
  const int b = blockIdx.x;
  const int lane = threadIdx.x;

  const float* hb = h + (size_t)b * T * N;

  // M row for this lane: M[lane][j] = exp(trans[lane*64+j])  (64 VGPRs)
  float Mrow[N];
  const float4* trow = (const float4*)(trans + lane * N);
#pragma unroll
  for (int q = 0; q < 16; ++q) {
    float4 tq = trow[q];
    Mrow[4 * q + 0] = __builtin_amdgcn_exp2f(tq.x * LOG2E);
    Mrow[4 * q + 1] = __builtin_amdgcn_exp2f(tq.y * LOG2E);
    Mrow[4 * q + 2] = __builtin_amdgcn_exp2f(tq.z * LOG2E);
    Mrow[4 * q + 3] = __builtin_amdgcn_exp2f(tq.w * LOG2E);
  }
  // Pin each M value into an arch VGPR (defeats AGPR-copy / remat / spill).
  // No instructions emitted; "+v" ties each scalar to a vector register.
#pragma unroll
  for (int q = 0; q < 8; ++q) {
    asm volatile("" : "+v"(Mrow[8 * q + 0]), "+v"(Mrow[8 * q + 1]),
                      "+v"(Mrow[8 * q + 2]), "+v"(Mrow[8 * q + 3]),
                      "+v"(Mrow[8 * q + 4]), "+v"(Mrow[8 * q + 5]),
                      "+v"(Mrow[8 * q + 6]), "+v"(Mrow[8 * q + 7]));
  }

  const int len = lengths[b];

  // Step t=0 closed form (exp(-10000+x)==0 in fp32): score[i]=h[b,0,i]+trans[i,START]
  float score2 = (hb[lane] + trans[lane * N + (N - 2)]) * LOG2E;

  auto step = [&](float emit2) {
    float a2 = __uint_as_float(
        __builtin_amdgcn_readfirstlane(__float_as_uint(score2)));
    float w = __builtin_amdgcn_exp2f(score2 - a2);
    float acc[8];
#pragma unroll
    for (int k = 0; k < 8; ++k) acc[k] = 0.0f;
#pragma unroll
    for (int j = 0; j < N; ++j) {
      acc[j & 7] = fmaf(Mrow[j], bcast(w, j), acc[j & 7]);
    }
    float s = ((acc[0] + acc[1]) + (acc[2] + acc[3])) +
              ((acc[4] + acc[5]) + (acc[6] + acc[7]));
    score2 = emit2 + a2 + __builtin_amdgcn_logf(s);  // v_log_f32 = log2
  };

  // Software-pipelined emissions (pre-scaled by log2e), 8 deep.
  float eb[8];
#pragma unroll
  for (int u = 0; u < 8; ++u) {
    int t0 = 1 + u;
    int tc = t0 < T ? t0 : T - 1;
    eb[u] = hb[(size_t)tc * N + lane] * LOG2E;
  }

  int t = 1;
  for (; t + 8 <= len; t += 8) {
#pragma unroll
    for (int u = 0; u < 8; ++u) {
      step(eb[u]);
      int tn = t + u + 8;
      int tc = tn < T ? tn : T - 1;  // in-bounds; value unused past len
      eb[u] = hb[(size_t)tc * N + lane] * LOG2E;
    }
  }
  for (; t < len; ++t) {  // <=7 tail steps
    step(hb[(size_t)t * N + lane] * LOG2E);
  }

  // Terminal transition to END (N-1), then wave-wide logsumexp (natural log out).
  float fin = score2 * LN2 + trans[(N - 1) * N + lane];
  float m = fin;
#pragma unroll
  for (int off = 32; off >= 1; off >>= 1)
    m = fmaxf(m, __shfl_xor(m, off, 64));
  float z = __builtin_amdgcn_exp2f((fin - m) * LOG2E);
#pragma unroll
  for (int off = 32; off >= 1; off >>= 1)
    z += __shfl_xor(z, off, 64);
  if (lane == 0) out[b] = m + LN2 * __builtin_amdgcn_logf(z);
}

extern "C" void kernel_launch(void* const* d_in, const int* in_sizes, int n_in,
                              void* d_out, int out_size, void* d_ws, size_t ws_size,
                              hipStream_t stream) {
  const float* h = (const float*)d_in[0];
  const float* trans = (const float*)d_in[1];
  const int* lengths = (const int*)d_in[2];
  float* out = (float*)d_out;
  const int B = in_sizes[2];
  const int N = 64;
  const int T = in_sizes[0] / (B * N);
  crf_fwd_33852932227637<<<B, 64, 0, stream>>>(h, trans, lengths, out, T);
}